// Round 4
// baseline (45.278 us; speedup 1.0000x reference)
//
#include <hip/hip_runtime.h>

#define BATCH 16
#define NPTS 4096
#define TOTN (BATCH * NPTS)   // 65536

// Pass 1: blocks = BATCH * S, S = NPTS/MC m-chunks. Each block: one batch b,
// all 4096 n (T=16 per thread), one MC-wide m-chunk staged in LDS as
// q_m = (-2x, -2y, -2z, |p_m|^2). Thread computes, for its 16 n's,
// min_m [ q_m . a_n + q_m.w ] with a_n = (-x_n, y_n, z_n), adds |a_n|^2,
// writes per-(chunk, n) partial distances to ws (coalesced).
template <int MC>
__global__ __launch_bounds__(256, 4) void chamfer_part_kernel(
    const float* __restrict__ xyz, float* __restrict__ partial) {
    constexpr int S = NPTS / MC;
    __shared__ float4 q[MC];

    const int s = blockIdx.x % S;
    const int b = blockIdx.x / S;
    const float* base = xyz + (size_t)b * 3 * NPTS;

    const int m0 = s * MC;
    for (int i = threadIdx.x; i < MC; i += 256) {
        float x = base[m0 + i];
        float y = base[NPTS + m0 + i];
        float z = base[2 * NPTS + m0 + i];
        q[i] = make_float4(-2.0f * x, -2.0f * y, -2.0f * z,
                           x * x + y * y + z * z);
    }
    __syncthreads();

    // This thread's 16 mirrored n-points (coalesced per j).
    float ax[16], ay[16], az[16], acc[16];
#pragma unroll
    for (int j = 0; j < 16; ++j) {
        int n = threadIdx.x + j * 256;
        ax[j] = -base[n];              // mirror across yz-plane
        ay[j] = base[NPTS + n];
        az[j] = base[2 * NPTS + n];
        acc[j] = 1e30f;
    }

    // Main loop: 1 broadcast LDS b128 read feeds 16 n's (4 VALU ops each).
    for (int m = 0; m < MC; m += 4) {
#pragma unroll
        for (int u = 0; u < 4; ++u) {
            float4 p = q[m + u];
#pragma unroll
            for (int j = 0; j < 16; ++j) {
                float t = fmaf(p.x, ax[j],
                          fmaf(p.y, ay[j],
                          fmaf(p.z, az[j], p.w)));
                acc[j] = fminf(acc[j], t);
            }
        }
    }

    // Add |a_n|^2 here so pass 2 is a pure min (commutes with cross-chunk min).
    float* dst = partial + (size_t)s * TOTN + b * NPTS + threadIdx.x;
#pragma unroll
    for (int j = 0; j < 16; ++j) {
        float a2 = fmaf(ax[j], ax[j], fmaf(ay[j], ay[j], az[j] * az[j]));
        dst[j * 256] = acc[j] + a2;
    }
}

// Pass 2: per n, min over S chunks, block-sum 256 n's.
__global__ __launch_bounds__(256) void combine_kernel(
    const float* __restrict__ partial, float* __restrict__ blocksums, int S) {
    __shared__ float red[4];
    const int n = blockIdx.x * 256 + threadIdx.x;   // 0..TOTN-1
    float v = 1e30f;
    for (int s = 0; s < S; ++s) v = fminf(v, partial[(size_t)s * TOTN + n]);

    float sum = v;
#pragma unroll
    for (int off = 32; off; off >>= 1) sum += __shfl_down(sum, off, 64);
    if ((threadIdx.x & 63) == 0) red[threadIdx.x >> 6] = sum;
    __syncthreads();
    if (threadIdx.x == 0)
        blocksums[blockIdx.x] = (red[0] + red[1]) + (red[2] + red[3]);
}

// Pass 3: 256 block sums -> scalar loss.
__global__ __launch_bounds__(256) void final_kernel(
    const float* __restrict__ blocksums, float* __restrict__ out) {
    __shared__ float red[4];
    float v = blocksums[threadIdx.x];
#pragma unroll
    for (int off = 32; off; off >>= 1) v += __shfl_down(v, off, 64);
    if ((threadIdx.x & 63) == 0) red[threadIdx.x >> 6] = v;
    __syncthreads();
    if (threadIdx.x == 0)
        out[0] = ((red[0] + red[1]) + (red[2] + red[3])) * (2.0f / (float)TOTN);
}

extern "C" void kernel_launch(void* const* d_in, const int* in_sizes, int n_in,
                              void* d_out, int out_size, void* d_ws, size_t ws_size,
                              hipStream_t stream) {
    const float* xyz = (const float*)d_in[0];
    float* out = (float*)d_out;
    float* partial = (float*)d_ws;

    // Pick S (m-chunks) by available workspace: need S*TOTN+256 floats.
    int S;
    if (ws_size >= (size_t)(64 * TOTN + 256) * 4) S = 64;
    else if (ws_size >= (size_t)(16 * TOTN + 256) * 4) S = 16;
    else if (ws_size >= (size_t)(4 * TOTN + 256) * 4) S = 4;
    else S = 1;
    float* blocksums = partial + (size_t)S * TOTN;

    const int nblocks = BATCH * S;
    switch (S) {
        case 64:
            chamfer_part_kernel<NPTS / 64><<<nblocks, 256, 0, stream>>>(xyz, partial);
            break;
        case 16:
            chamfer_part_kernel<NPTS / 16><<<nblocks, 256, 0, stream>>>(xyz, partial);
            break;
        case 4:
            chamfer_part_kernel<NPTS / 4><<<nblocks, 256, 0, stream>>>(xyz, partial);
            break;
        default:
            chamfer_part_kernel<NPTS><<<nblocks, 256, 0, stream>>>(xyz, partial);
            break;
    }
    combine_kernel<<<TOTN / 256, 256, 0, stream>>>(partial, blocksums, S);
    final_kernel<<<1, 256, 0, stream>>>(blocksums, out);
}

// Round 7
// 26.556 us; speedup vs baseline: 1.7050x; 1.7050x over previous
//
#include <hip/hip_runtime.h>

#define BATCH 16
#define NPTS 4096
#define TOTN (BATCH * NPTS)   // 65536

typedef _Float16 f16;
typedef __attribute__((ext_vector_type(8))) _Float16 f16x8;
typedef __attribute__((ext_vector_type(16))) float f32x16;

__device__ __forceinline__ unsigned pk(f16 a, f16 b) {
    union { f16 h[2]; unsigned u; } t;
    t.h[0] = a; t.h[1] = b;   // h[0] -> low 16 bits = even k slot
    return t.u;
}

// One block per (batch, 256-n supertile); 4 waves, each wave owns 64 n.
// A-side (rows = m): K-slots per m with c = -2*p_m, b2 = |p_m|^2:
//   k0..8  = [cxh,cxh,cxl, cyh,cyh,cyl, czh,czh,czl]
//   k9,k10 = [b2h, b2l], k11..15 = 0
// B-side (cols = n): a_n = (-x_n, y_n, z_n) mirrored:
//   k0..8  = [axh,axl,axh, ayh,ayl,ayh, azh,azl,azh]
//   k9,k10 = [1, 1], k11..15 = 0
// => D[m][n] = |p_m|^2 - 2 a_n.p_m  (error ~2^-22). min over m in registers.
__global__ __launch_bounds__(256) void chamfer_mfma_kernel(
    const float* __restrict__ xyz, float* __restrict__ partials) {
    __shared__ uint4 T0[NPTS];   // A-frag k0..7  per m (64 KB)
    __shared__ uint4 T1[NPTS];   // A-frag k8..15 per m (64 KB)

    const int tid = threadIdx.x;
    const int lane = tid & 63;
    const int wid = tid >> 6;
    const int lm = lane & 31;
    const int kh = lane >> 5;          // which k-half this lane supplies

    const int b = blockIdx.x >> 4;
    const int nsup = blockIdx.x & 15;
    const float* base = xyz + (size_t)b * 3 * NPTS;

    // Stage expanded A-side fragments for all 4096 m of this batch.
    for (int i = tid; i < NPTS; i += 256) {
        float x = base[i], y = base[NPTS + i], z = base[2 * NPTS + i];
        float cx = -2.f * x, cy = -2.f * y, cz = -2.f * z;
        float b2 = fmaf(x, x, fmaf(y, y, z * z));
        f16 cxh = (f16)cx; f16 cxl = (f16)(cx - (float)cxh);
        f16 cyh = (f16)cy; f16 cyl = (f16)(cy - (float)cyh);
        f16 czh = (f16)cz; f16 czl = (f16)(cz - (float)czh);
        f16 b2h = (f16)b2; f16 b2l = (f16)(b2 - (float)b2h);
        T0[i] = make_uint4(pk(cxh, cxh), pk(cxl, cyh), pk(cyh, cyl), pk(czh, czh));
        T1[i] = make_uint4(pk(czl, b2h), pk(b2l, (f16)0.f), 0u, 0u);
    }
    __syncthreads();

    // B-side fragments for this wave's two 32-n tiles.
    const int n0 = nsup * 256 + wid * 64;
    f16x8 B0, B1;
    {
#pragma unroll
        for (int tile = 0; tile < 2; ++tile) {
            int n = n0 + tile * 32 + lm;
            float ax = -base[n];               // mirror across yz-plane
            float ay = base[NPTS + n];
            float az = base[2 * NPTS + n];
            f16 axh = (f16)ax; f16 axl = (f16)(ax - (float)axh);
            f16 ayh = (f16)ay; f16 ayl = (f16)(ay - (float)ayh);
            f16 azh = (f16)az; f16 azl = (f16)(az - (float)azh);
            union { unsigned u[4]; f16x8 v; } B;
            if (kh == 0) {
                B.u[0] = pk(axh, axl); B.u[1] = pk(axh, ayh);
                B.u[2] = pk(ayl, ayh); B.u[3] = pk(azh, azl);
            } else {
                B.u[0] = pk(azh, (f16)1.f); B.u[1] = pk((f16)1.f, (f16)0.f);
                B.u[2] = 0u; B.u[3] = 0u;
            }
            if (tile == 0) B0 = B.v; else B1 = B.v;
        }
    }

    const uint4* Ab = kh ? T1 : T0;    // uniform instruction, per-lane base
    f32x16 mn0, mn1;
#pragma unroll
    for (int r = 0; r < 16; ++r) { mn0[r] = 1e30f; mn1[r] = 1e30f; }
    const f32x16 zero = {};

#pragma unroll 2
    for (int t = 0; t < NPTS / 32; ++t) {
        union { uint4 q; f16x8 v; } A;
        A.q = Ab[t * 32 + lm];         // row m = t*32 + lm, this lane's k-half
        f32x16 d0 = __builtin_amdgcn_mfma_f32_32x32x16_f16(A.v, B0, zero, 0, 0, 0);
        f32x16 d1 = __builtin_amdgcn_mfma_f32_32x32x16_f16(A.v, B1, zero, 0, 0, 0);
#pragma unroll
        for (int r = 0; r < 16; ++r) {
            mn0[r] = fminf(mn0[r], d0[r]);
            mn1[r] = fminf(mn1[r], d1[r]);
        }
    }

    // Reduce 16 regs (rows within half) then combine row-halves across lane^32.
    float v0 = mn0[0], v1 = mn1[0];
#pragma unroll
    for (int r = 1; r < 16; ++r) { v0 = fminf(v0, mn0[r]); v1 = fminf(v1, mn1[r]); }
    v0 = fminf(v0, __shfl_xor(v0, 32, 64));
    v1 = fminf(v1, __shfl_xor(v1, 32, 64));

    // Add |a_n|^2 per column, sum over this wave's 64 n (each col duplicated x2).
    int na = n0 + lm, nb = n0 + 32 + lm;
    float xa = base[na], ya = base[NPTS + na], za = base[2 * NPTS + na];
    float xb = base[nb], yb = base[NPTS + nb], zb = base[2 * NPTS + nb];
    float s = (v0 + fmaf(xa, xa, fmaf(ya, ya, za * za)))
            + (v1 + fmaf(xb, xb, fmaf(yb, yb, zb * zb)));
#pragma unroll
    for (int off = 1; off < 64; off <<= 1) s += __shfl_xor(s, off, 64);
    if (lane == 0) partials[blockIdx.x * 4 + wid] = s * 0.5f;
}

// Reduce 1024 wave partials -> scalar loss.
__global__ __launch_bounds__(256) void final_kernel(
    const float* __restrict__ partials, float* __restrict__ out) {
    __shared__ float red[4];
    float v = partials[threadIdx.x] + partials[256 + threadIdx.x]
            + partials[512 + threadIdx.x] + partials[768 + threadIdx.x];
#pragma unroll
    for (int off = 32; off; off >>= 1) v += __shfl_down(v, off, 64);
    if ((threadIdx.x & 63) == 0) red[threadIdx.x >> 6] = v;
    __syncthreads();
    if (threadIdx.x == 0)
        out[0] = ((red[0] + red[1]) + (red[2] + red[3])) * (2.0f / (float)TOTN);
}

extern "C" void kernel_launch(void* const* d_in, const int* in_sizes, int n_in,
                              void* d_out, int out_size, void* d_ws, size_t ws_size,
                              hipStream_t stream) {
    const float* xyz = (const float*)d_in[0];
    float* out = (float*)d_out;
    float* partials = (float*)d_ws;   // 1024 floats

    chamfer_mfma_kernel<<<BATCH * 16, 256, 0, stream>>>(xyz, partials);
    final_kernel<<<1, 256, 0, stream>>>(partials, out);
}

// Round 9
// 19.340 us; speedup vs baseline: 2.3411x; 1.3731x over previous
//
#include <hip/hip_runtime.h>

#define BATCH 16
#define NPTS 4096
#define TOTN (BATCH * NPTS)   // 65536
#define MH 8                  // m-chunks per batch
#define MC (NPTS / MH)        // 512 m per block

typedef _Float16 f16;
typedef __attribute__((ext_vector_type(8))) _Float16 f16x8;
typedef __attribute__((ext_vector_type(16))) float f32x16;

__device__ __forceinline__ unsigned pk(f16 a, f16 b) {
    union { f16 h[2]; unsigned u; } t;
    t.h[0] = a; t.h[1] = b;   // h[0] -> low 16 bits = even k slot
    return t.u;
}

__device__ __forceinline__ float min3f(float a, float b, float c) {
    return fminf(fminf(a, b), c);   // clang fuses to v_min3_f32
}

// Min over the 16 C/D regs (rows of one 32-col tile) then into acc: 8x min3.
__device__ __forceinline__ float treemin(const f32x16& d, float acc) {
    float t0 = min3f(d[0], d[1], d[2]);
    float t1 = min3f(d[3], d[4], d[5]);
    float t2 = min3f(d[6], d[7], d[8]);
    float t3 = min3f(d[9], d[10], d[11]);
    float t4 = min3f(d[12], d[13], d[14]);
    float u0 = min3f(t0, t1, t2);
    float u1 = min3f(t3, t4, d[15]);
    return min3f(acc, u0, u1);
}

// Grid = BATCH * 8 nsup * MH = 1024 blocks (4 blocks/CU, 16 waves/CU).
// Block: batch b, 512-n supertile, 512-m chunk staged in LDS (16 KB).
// Wave: 128 n as 4 column-tiles of 32; per m-iter one ds_read_b128 feeds
// 4 MFMAs; per-tile scalar min-acc via v_min3 trees.
// A-side k-slots (c = -2 p_m, b2 = |p_m|^2):
//   k0..8 = [cxh,cxh,cxl, cyh,cyh,cyl, czh,czh,czl], k9,k10 = [b2h,b2l]
// B-side (a_n = mirrored point): k0..8 = [axh,axl,axh, ayh,ayl,ayh, azh,azl,azh],
//   k9,k10 = [1,1]  =>  D[m][n] = |p_m|^2 - 2 a_n.p_m  (err ~2^-22)
__global__ __launch_bounds__(256, 4) void chamfer_mfma_kernel(
    const float* __restrict__ xyz, float* __restrict__ partials) {
    __shared__ uint4 T0[MC];   // A-frag k0..7  per m (8 KB)
    __shared__ uint4 T1[MC];   // A-frag k8..15 per m (8 KB)

    const int tid = threadIdx.x;
    const int lane = tid & 63;
    const int wid = tid >> 6;
    const int lm = lane & 31;
    const int kh = lane >> 5;          // which k-half this lane supplies

    const int mh = blockIdx.x & 7;
    const int nsup = (blockIdx.x >> 3) & 7;
    const int b = blockIdx.x >> 6;
    const float* base = xyz + (size_t)b * 3 * NPTS;

    // Stage expanded A-side fragments for this block's 512 m.
    const int m0 = mh * MC;
    for (int i = tid; i < MC; i += 256) {
        int mg = m0 + i;
        float x = base[mg], y = base[NPTS + mg], z = base[2 * NPTS + mg];
        float cx = -2.f * x, cy = -2.f * y, cz = -2.f * z;
        float b2 = fmaf(x, x, fmaf(y, y, z * z));
        f16 cxh = (f16)cx; f16 cxl = (f16)(cx - (float)cxh);
        f16 cyh = (f16)cy; f16 cyl = (f16)(cy - (float)cyh);
        f16 czh = (f16)cz; f16 czl = (f16)(cz - (float)czh);
        f16 b2h = (f16)b2; f16 b2l = (f16)(b2 - (float)b2h);
        T0[i] = make_uint4(pk(cxh, cxh), pk(cxl, cyh), pk(cyh, cyl), pk(czh, czh));
        T1[i] = make_uint4(pk(czl, b2h), pk(b2l, (f16)0.f), 0u, 0u);
    }
    __syncthreads();

    // B-side fragments for this wave's four 32-n tiles.
    const int n0 = nsup * 512 + wid * 128;
    f16x8 Bf[4];
#pragma unroll
    for (int tile = 0; tile < 4; ++tile) {
        int n = n0 + tile * 32 + lm;
        float ax = -base[n];               // mirror across yz-plane
        float ay = base[NPTS + n];
        float az = base[2 * NPTS + n];
        f16 axh = (f16)ax; f16 axl = (f16)(ax - (float)axh);
        f16 ayh = (f16)ay; f16 ayl = (f16)(ay - (float)ayh);
        f16 azh = (f16)az; f16 azl = (f16)(az - (float)azh);
        union { unsigned u[4]; f16x8 v; } B;
        if (kh == 0) {
            B.u[0] = pk(axh, axl); B.u[1] = pk(axh, ayh);
            B.u[2] = pk(ayl, ayh); B.u[3] = pk(azh, azl);
        } else {
            B.u[0] = pk(azh, (f16)1.f); B.u[1] = pk((f16)1.f, (f16)0.f);
            B.u[2] = 0u; B.u[3] = 0u;
        }
        Bf[tile] = B.v;
    }

    const uint4* Ab = kh ? T1 : T0;    // uniform instruction, per-lane base
    float acc0 = 1e30f, acc1 = 1e30f, acc2 = 1e30f, acc3 = 1e30f;
    const f32x16 zero = {};

#pragma unroll 2
    for (int t = 0; t < MC / 32; ++t) {
        union { uint4 q; f16x8 v; } A;
        A.q = Ab[t * 32 + lm];         // row m = t*32 + lm, this lane's k-half
        f32x16 d0 = __builtin_amdgcn_mfma_f32_32x32x16_f16(A.v, Bf[0], zero, 0, 0, 0);
        f32x16 d1 = __builtin_amdgcn_mfma_f32_32x32x16_f16(A.v, Bf[1], zero, 0, 0, 0);
        f32x16 d2 = __builtin_amdgcn_mfma_f32_32x32x16_f16(A.v, Bf[2], zero, 0, 0, 0);
        f32x16 d3 = __builtin_amdgcn_mfma_f32_32x32x16_f16(A.v, Bf[3], zero, 0, 0, 0);
        acc0 = treemin(d0, acc0);
        acc1 = treemin(d1, acc1);
        acc2 = treemin(d2, acc2);
        acc3 = treemin(d3, acc3);
    }

    // Combine row-halves (lane vs lane^32 hold complementary rows of each col).
    acc0 = fminf(acc0, __shfl_xor(acc0, 32, 64));
    acc1 = fminf(acc1, __shfl_xor(acc1, 32, 64));
    acc2 = fminf(acc2, __shfl_xor(acc2, 32, 64));
    acc3 = fminf(acc3, __shfl_xor(acc3, 32, 64));

    if (lane < 32) {
        float* dst = partials + (size_t)mh * TOTN + b * NPTS + n0 + lm;
        dst[0] = acc0;
        dst[32] = acc1;
        dst[64] = acc2;
        dst[96] = acc3;
    }
}

// Pass 2: per n, min over MH chunks, add |a_n|^2, block-sum 256 n's.
__global__ __launch_bounds__(256) void combine_kernel(
    const float* __restrict__ xyz, const float* __restrict__ partials,
    float* __restrict__ blocksums) {
    __shared__ float red[4];
    const int n = blockIdx.x * 256 + threadIdx.x;   // 0..TOTN-1
    float v = partials[n];
#pragma unroll
    for (int s = 1; s < MH; ++s) v = fminf(v, partials[(size_t)s * TOTN + n]);

    const int b = n >> 12;
    const int i = n & (NPTS - 1);
    const float* base = xyz + (size_t)b * 3 * NPTS;
    float x = base[i], y = base[NPTS + i], z = base[2 * NPTS + i];
    float sum = v + fmaf(x, x, fmaf(y, y, z * z));

#pragma unroll
    for (int off = 32; off; off >>= 1) sum += __shfl_down(sum, off, 64);
    if ((threadIdx.x & 63) == 0) red[threadIdx.x >> 6] = sum;
    __syncthreads();
    if (threadIdx.x == 0)
        blocksums[blockIdx.x] = (red[0] + red[1]) + (red[2] + red[3]);
}

// Pass 3: 256 block sums -> scalar loss.
__global__ __launch_bounds__(256) void final_kernel(
    const float* __restrict__ blocksums, float* __restrict__ out) {
    __shared__ float red[4];
    float v = blocksums[threadIdx.x];
#pragma unroll
    for (int off = 32; off; off >>= 1) v += __shfl_down(v, off, 64);
    if ((threadIdx.x & 63) == 0) red[threadIdx.x >> 6] = v;
    __syncthreads();
    if (threadIdx.x == 0)
        out[0] = ((red[0] + red[1]) + (red[2] + red[3])) * (2.0f / (float)TOTN);
}

extern "C" void kernel_launch(void* const* d_in, const int* in_sizes, int n_in,
                              void* d_out, int out_size, void* d_ws, size_t ws_size,
                              hipStream_t stream) {
    const float* xyz = (const float*)d_in[0];
    float* out = (float*)d_out;
    float* partials = (float*)d_ws;                 // MH*TOTN floats (2 MB)
    float* blocksums = partials + (size_t)MH * TOTN; // +256 floats

    chamfer_mfma_kernel<<<BATCH * 8 * MH, 256, 0, stream>>>(xyz, partials);
    combine_kernel<<<TOTN / 256, 256, 0, stream>>>(xyz, partials, blocksums);
    final_kernel<<<1, 256, 0, stream>>>(blocksums, out);
}